// Round 1
// baseline (113.372 us; speedup 1.0000x reference)
//
#include <hip/hip_runtime.h>
#include <hip/hip_bf16.h>

#define B_   4
#define N_   1024
#define H_   16
#define HID_ 64
#define TI   16
#define TJ   64
#define UST  68   // padded LDS row stride (floats): breaks 256B-stride bank conflicts

typedef float f32x4  __attribute__((ext_vector_type(4)));
typedef short bf16x8 __attribute__((ext_vector_type(8)));

static __device__ __forceinline__ short f2bf(float f) {
    // round-to-nearest-even fp32 -> bf16 (inputs are finite)
    unsigned u = __float_as_uint(f);
    u += 0x7fffu + ((u >> 16) & 1u);
    return (short)(u >> 16);
}

__global__ __launch_bounds__(256) void RelativePositionalBias_kernel(
    const float* __restrict__ pos,  // (B,N,2)
    const int*   __restrict__ mask, // (B,N) 0/1
    const float* __restrict__ W1,   // (2,64)
    const float* __restrict__ b1,   // (64)
    const float* __restrict__ W2,   // (64,64)
    const float* __restrict__ b2,   // (64)
    const float* __restrict__ W3,   // (64,16)
    const float* __restrict__ b3,   // (16)
    float* __restrict__ out)        // (B,16,N,N)
{
    __shared__ float uj[TJ][UST];       // u = pos@W1 for j-rows of tile
    __shared__ float ui[TI][UST];       // u for i-rows of tile
    __shared__ float h2s[4][16][UST];   // per-wave h2 re-fragmentation buffer

    const int b  = blockIdx.z;
    const int i0 = blockIdx.y * TI;
    const int j0 = blockIdx.x * TJ;
    const int tid = threadIdx.x;
    const int w = tid >> 6;      // wave 0..3
    const int l = tid & 63;
    const int g = l >> 4;        // quarter-wave group 0..3
    const int c = l & 15;        // lane-within-group 0..15

    // ---- Stage u = pos @ W1 for the 80 tokens this tile touches ----
    for (int it = tid; it < (TJ + TI) * 16; it += 256) {
        int r  = it >> 4;
        int kq = (it & 15) * 4;
        int tok = (r < TJ) ? (j0 + r) : (i0 + (r - TJ));
        float2 p  = *(const float2*)&pos[(b * N_ + tok) * 2];
        float4 w0 = *(const float4*)&W1[kq];          // W1[0][kq..]
        float4 w1 = *(const float4*)&W1[HID_ + kq];   // W1[1][kq..]
        float4 v;
        v.x = p.x * w0.x + p.y * w1.x;
        v.y = p.x * w0.y + p.y * w1.y;
        v.z = p.x * w0.z + p.y * w1.z;
        v.w = p.x * w0.w + p.y * w1.w;
        if (r < TJ) *(float4*)&uj[r][kq] = v;
        else        *(float4*)&ui[r - TJ][kq] = v;
    }

    // ---- Preload weight fragments (per-lane) ----
    // A/B fragment convention: element (g,i) <-> k = 32*s + 8*g + i (consistent for A and B)
    bf16x8 W2f[2][4];   // B-frag: W2[k][16n + c]
    #pragma unroll
    for (int s = 0; s < 2; ++s)
        #pragma unroll
        for (int n = 0; n < 4; ++n)
            #pragma unroll
            for (int i = 0; i < 8; ++i)
                W2f[s][n][i] = f2bf(W2[(32*s + 8*g + i) * HID_ + 16*n + c]);

    bf16x8 W3f[2];      // B-frag: W3[k][c]  (N-dim = 16 heads)
    #pragma unroll
    for (int s = 0; s < 2; ++s)
        #pragma unroll
        for (int i = 0; i < 8; ++i)
            W3f[s][i] = f2bf(W3[(32*s + 8*g + i) * H_ + c]);

    float b1v[2][8];
    #pragma unroll
    for (int s = 0; s < 2; ++s)
        #pragma unroll
        for (int i = 0; i < 8; ++i)
            b1v[s][i] = b1[32*s + 8*g + i];

    float b2v[4];
    #pragma unroll
    for (int n = 0; n < 4; ++n) b2v[n] = b2[16*n + c];
    const float b3v = b3[c];

    // lane's 4 output columns: j = j0 + 16*w + 4*g + q
    const int4 mj = *(const int4*)&mask[b * N_ + j0 + 16*w + 4*g];

    __syncthreads();

    const float* pj = &uj[16*w + c][0];  // this lane's j-row (pair row r = c)

    for (int t = 0; t < TI; ++t) {
        const int maski = mask[b * N_ + i0 + t];

        // ---- Build layer-1 A fragments: h1 = relu(u_j - u_i + b1) ----
        bf16x8 A1[2];
        #pragma unroll
        for (int s = 0; s < 2; ++s) {
            const int kb = 32*s + 8*g;
            float4 ja = *(const float4*)&pj[kb];
            float4 jb = *(const float4*)&pj[kb + 4];
            float4 ia = *(const float4*)&ui[t][kb];
            float4 ib = *(const float4*)&ui[t][kb + 4];
            A1[s][0] = f2bf(fmaxf(ja.x - ia.x + b1v[s][0], 0.f));
            A1[s][1] = f2bf(fmaxf(ja.y - ia.y + b1v[s][1], 0.f));
            A1[s][2] = f2bf(fmaxf(ja.z - ia.z + b1v[s][2], 0.f));
            A1[s][3] = f2bf(fmaxf(ja.w - ia.w + b1v[s][3], 0.f));
            A1[s][4] = f2bf(fmaxf(jb.x - ib.x + b1v[s][4], 0.f));
            A1[s][5] = f2bf(fmaxf(jb.y - ib.y + b1v[s][5], 0.f));
            A1[s][6] = f2bf(fmaxf(jb.z - ib.z + b1v[s][6], 0.f));
            A1[s][7] = f2bf(fmaxf(jb.w - ib.w + b1v[s][7], 0.f));
        }

        // ---- Layer 2: (16 pairs x 64) = h1 @ W2 ----
        f32x4 acc[4];
        #pragma unroll
        for (int n = 0; n < 4; ++n) {
            f32x4 z = {0.f, 0.f, 0.f, 0.f};
            z      = __builtin_amdgcn_mfma_f32_16x16x32_bf16(A1[0], W2f[0][n], z, 0, 0, 0);
            acc[n] = __builtin_amdgcn_mfma_f32_16x16x32_bf16(A1[1], W2f[1][n], z, 0, 0, 0);
        }

        // ---- bias + relu, round-trip h2 through wave-private LDS ----
        // D layout: value (row = 4g+q, col = 16n+c)
        #pragma unroll
        for (int n = 0; n < 4; ++n)
            #pragma unroll
            for (int q = 0; q < 4; ++q)
                h2s[w][4*g + q][16*n + c] = fmaxf(acc[n][q] + b2v[n], 0.f);

        // ---- Build layer-3 A fragments from LDS (compiler inserts lgkmcnt waits) ----
        bf16x8 A3[2];
        #pragma unroll
        for (int s = 0; s < 2; ++s) {
            const int kb = 32*s + 8*g;
            float4 a  = *(const float4*)&h2s[w][c][kb];
            float4 bb = *(const float4*)&h2s[w][c][kb + 4];
            A3[s][0] = f2bf(a.x);  A3[s][1] = f2bf(a.y);
            A3[s][2] = f2bf(a.z);  A3[s][3] = f2bf(a.w);
            A3[s][4] = f2bf(bb.x); A3[s][5] = f2bf(bb.y);
            A3[s][6] = f2bf(bb.z); A3[s][7] = f2bf(bb.w);
        }

        // ---- Layer 3: (16 pairs x 16 heads) = h2 @ W3 + b3 ----
        f32x4 acc3 = {b3v, b3v, b3v, b3v};
        acc3 = __builtin_amdgcn_mfma_f32_16x16x32_bf16(A3[0], W3f[0], acc3, 0, 0, 0);
        acc3 = __builtin_amdgcn_mfma_f32_16x16x32_bf16(A3[1], W3f[1], acc3, 0, 0, 0);

        // ---- Mask + store: lane holds out[b][h=c][i0+t][j0+16w+4g + q], q=0..3 ----
        float4 o;
        o.x = (maski | mj.x) ? 0.f : acc3[0];
        o.y = (maski | mj.y) ? 0.f : acc3[1];
        o.z = (maski | mj.z) ? 0.f : acc3[2];
        o.w = (maski | mj.w) ? 0.f : acc3[3];
        size_t off = ((size_t)((b*H_ + c) * N_ + i0 + t) << 10) + (size_t)(j0 + 16*w + 4*g);
        *(float4*)&out[off] = o;
    }
}

extern "C" void kernel_launch(void* const* d_in, const int* in_sizes, int n_in,
                              void* d_out, int out_size, void* d_ws, size_t ws_size,
                              hipStream_t stream) {
    const float* pos  = (const float*)d_in[0];
    const int*   mask = (const int*)d_in[1];
    const float* W1   = (const float*)d_in[2];
    const float* b1   = (const float*)d_in[3];
    const float* W2   = (const float*)d_in[4];
    const float* b2   = (const float*)d_in[5];
    const float* W3   = (const float*)d_in[6];
    const float* b3   = (const float*)d_in[7];
    float* out = (float*)d_out;

    dim3 grid(N_ / TJ, N_ / TI, B_);
    RelativePositionalBias_kernel<<<grid, dim3(256), 0, stream>>>(
        pos, mask, W1, b1, W2, b2, W3, b3, out);
}

// Round 2
// 83.997 us; speedup vs baseline: 1.3497x; 1.3497x over previous
//
#include <hip/hip_runtime.h>
#include <hip/hip_bf16.h>

#define B_   4
#define N_   1024
#define H_   16
#define HID_ 64
#define TI   16
#define TJ   64
#define UST  68   // padded LDS row stride (floats)

typedef float f32x4  __attribute__((ext_vector_type(4)));
typedef short bf16x8 __attribute__((ext_vector_type(8)));

static __device__ __forceinline__ short f2bf(float f) {
    // native converter -> hardware v_cvt (RNE); compiler packs pairs into v_cvt_pk_bf16_f32
    union { __hip_bfloat16 h; short s; } u;
    u.h = __float2bfloat16(f);
    return u.s;
}

__global__ __launch_bounds__(256) void RelativePositionalBias_kernel(
    const float* __restrict__ pos,  // (B,N,2)
    const int*   __restrict__ mask, // (B,N) 0/1
    const float* __restrict__ W1,   // (2,64)
    const float* __restrict__ b1,   // (64)
    const float* __restrict__ W2,   // (64,64)
    const float* __restrict__ b2,   // (64)
    const float* __restrict__ W3,   // (64,16)
    const float* __restrict__ b3,   // (16)
    float* __restrict__ out)        // (B,16,N,N)
{
    __shared__ __align__(16) float uj[TJ][UST];   // u_j = pos_j @ W1
    __shared__ __align__(16) float uin[TI][UST];  // b1 - u_i  (bias folded at staging)

    const int b  = blockIdx.z;
    const int i0 = blockIdx.y * TI;
    const int j0 = blockIdx.x * TJ;
    const int tid = threadIdx.x;
    const int w = tid >> 6;      // wave 0..3
    const int l = tid & 63;
    const int g = l >> 4;        // quarter-wave group 0..3
    const int c = l & 15;        // lane-within-group 0..15

    // ---- Stage u = pos @ W1 for the 80 tokens this tile touches ----
    for (int it = tid; it < (TJ + TI) * 16; it += 256) {
        int r  = it >> 4;
        int kq = (it & 15) * 4;
        int tok = (r < TJ) ? (j0 + r) : (i0 + (r - TJ));
        float2 p  = *(const float2*)&pos[(b * N_ + tok) * 2];
        float4 w0 = *(const float4*)&W1[kq];          // W1[0][kq..]
        float4 w1 = *(const float4*)&W1[HID_ + kq];   // W1[1][kq..]
        float4 v;
        v.x = p.x * w0.x + p.y * w1.x;
        v.y = p.x * w0.y + p.y * w1.y;
        v.z = p.x * w0.z + p.y * w1.z;
        v.w = p.x * w0.w + p.y * w1.w;
        if (r < TJ) {
            *(float4*)&uj[r][kq] = v;
        } else {
            float4 bb = *(const float4*)&b1[kq];
            float4 t2 = { bb.x - v.x, bb.y - v.y, bb.z - v.z, bb.w - v.w };
            *(float4*)&uin[r - TJ][kq] = t2;
        }
    }

    // ---- Weight fragments ----
    // Layer2 (transposed trick): A = W2^T chunk n, identity k-map k=32s+8g+e.
    // W2f[s][n][e] = W2[32s+8g+e][16n+c] — serves as the A-fragment of mfma(W2^T, h1^T).
    bf16x8 W2f[2][4];
    #pragma unroll
    for (int s = 0; s < 2; ++s)
        #pragma unroll
        for (int n = 0; n < 4; ++n)
            #pragma unroll
            for (int e = 0; e < 8; ++e)
                W2f[s][n][e] = f2bf(W2[(32*s + 8*g + e) * HID_ + 16*n + c]);

    // Layer3 B-frag with PERMUTED k-map: hid(s,g,e) = 32s + 16*(e>>2) + 4g + (e&3)
    // (matches exactly what the lane holds from transposed layer2 -> no LDS round trip)
    bf16x8 W3g[2];
    #pragma unroll
    for (int s = 0; s < 2; ++s)
        #pragma unroll
        for (int e = 0; e < 8; ++e)
            W3g[s][e] = f2bf(W3[(32*s + 16*(e>>2) + 4*g + (e&3)) * H_ + c]);

    // b2 folded into layer2 accumulator init: b2v[n][q] = b2[16n+4g+q]
    f32x4 b2v[4];
    #pragma unroll
    for (int n = 0; n < 4; ++n)
        b2v[n] = *(const f32x4*)&b2[16*n + 4*g];

    const float b3v = b3[c];
    const int4 mj = *(const int4*)&mask[b * N_ + j0 + 16*w + 4*g];
    const int* maskb = &mask[b * N_ + i0];

    __syncthreads();

    // Hoist this lane's j-row of u (loop-invariant): k in {8g..8g+7} u {32+8g..}
    const float* pj = &uj[16*w + c][0];
    const f32x4 pj00 = *(const f32x4*)&pj[8*g];
    const f32x4 pj01 = *(const f32x4*)&pj[8*g + 4];
    const f32x4 pj10 = *(const f32x4*)&pj[32 + 8*g];
    const f32x4 pj11 = *(const f32x4*)&pj[32 + 8*g + 4];

    for (int t = 0; t < TI; ++t) {
        // broadcast reads of (b1 - u_i) for row i0+t
        const float* uip = &uin[t][0];
        f32x4 ui00 = *(const f32x4*)&uip[8*g];
        f32x4 ui01 = *(const f32x4*)&uip[8*g + 4];
        f32x4 ui10 = *(const f32x4*)&uip[32 + 8*g];
        f32x4 ui11 = *(const f32x4*)&uip[32 + 8*g + 4];

        // h1 fragment (dual-use A/B layout): h1[pair c][k 32s+8g+e]
        bf16x8 A1[2];
        #pragma unroll
        for (int e = 0; e < 4; ++e) {
            A1[0][e]     = f2bf(fmaxf(pj00[e] + ui00[e], 0.f));
            A1[0][e + 4] = f2bf(fmaxf(pj01[e] + ui01[e], 0.f));
            A1[1][e]     = f2bf(fmaxf(pj10[e] + ui10[e], 0.f));
            A1[1][e + 4] = f2bf(fmaxf(pj11[e] + ui11[e], 0.f));
        }

        // Layer2 TRANSPOSED: h2^T = W2^T @ h1^T; acc init = b2.
        // Lane (g,c) gets h2pre[pair c][hid 16n+4g+q] in acc[n][q].
        f32x4 acc[4];
        #pragma unroll
        for (int n = 0; n < 4; ++n) {
            acc[n] = __builtin_amdgcn_mfma_f32_16x16x32_bf16(W2f[0][n], A1[0], b2v[n], 0, 0, 0);
            acc[n] = __builtin_amdgcn_mfma_f32_16x16x32_bf16(W2f[1][n], A1[1], acc[n], 0, 0, 0);
        }

        // Layer3 A-fragment DIRECTLY from acc via the permuted k-map (register-only):
        // A3[s][e] = relu(acc[2s + (e>>2)][e&3])  <-> hid = 32s + 16(e>>2) + 4g + (e&3)
        bf16x8 A3[2];
        #pragma unroll
        for (int s = 0; s < 2; ++s)
            #pragma unroll
            for (int e = 0; e < 4; ++e) {
                A3[s][e]     = f2bf(fmaxf(acc[2*s][e],     0.f));
                A3[s][e + 4] = f2bf(fmaxf(acc[2*s + 1][e], 0.f));
            }

        // Layer3: out = h2 @ W3 (+b3). D: lane (g,c) = out[pair 4g+q][head c]
        f32x4 acc3 = { b3v, b3v, b3v, b3v };
        acc3 = __builtin_amdgcn_mfma_f32_16x16x32_bf16(A3[0], W3g[0], acc3, 0, 0, 0);
        acc3 = __builtin_amdgcn_mfma_f32_16x16x32_bf16(A3[1], W3g[1], acc3, 0, 0, 0);

        // Mask + store: lane holds out[b][h=c][i0+t][j0+16w+4g+q]
        float4 o;
        if (maskb[t]) {           // wave-uniform branch
            o.x = 0.f; o.y = 0.f; o.z = 0.f; o.w = 0.f;
        } else {
            o.x = mj.x ? 0.f : acc3[0];
            o.y = mj.y ? 0.f : acc3[1];
            o.z = mj.z ? 0.f : acc3[2];
            o.w = mj.w ? 0.f : acc3[3];
        }
        size_t off = ((size_t)((b*H_ + c) * N_ + i0 + t) << 10) + (size_t)(j0 + 16*w + 4*g);
        *(float4*)&out[off] = o;
    }
}

extern "C" void kernel_launch(void* const* d_in, const int* in_sizes, int n_in,
                              void* d_out, int out_size, void* d_ws, size_t ws_size,
                              hipStream_t stream) {
    const float* pos  = (const float*)d_in[0];
    const int*   mask = (const int*)d_in[1];
    const float* W1   = (const float*)d_in[2];
    const float* b1   = (const float*)d_in[3];
    const float* W2   = (const float*)d_in[4];
    const float* b2   = (const float*)d_in[5];
    const float* W3   = (const float*)d_in[6];
    const float* b3   = (const float*)d_in[7];
    float* out = (float*)d_out;

    dim3 grid(N_ / TJ, N_ / TI, B_);
    RelativePositionalBias_kernel<<<grid, dim3(256), 0, stream>>>(
        pos, mask, W1, b1, W2, b2, W3, b3, out);
}

// Round 3
// 82.124 us; speedup vs baseline: 1.3805x; 1.0228x over previous
//
#include <hip/hip_runtime.h>
#include <hip/hip_bf16.h>

#define B_   4
#define N_   1024
#define H_   16
#define HID_ 64
#define TI   16
#define TJ   64
#define UST  68   // padded LDS row stride (floats)

typedef float f32x4  __attribute__((ext_vector_type(4)));
typedef short bf16x8 __attribute__((ext_vector_type(8)));

static __device__ __forceinline__ short f2bf(float f) {
    union { __hip_bfloat16 h; short s; } u;
    u.h = __float2bfloat16(f);
    return u.s;
}

__global__ __launch_bounds__(256) void RelativePositionalBias_kernel(
    const float* __restrict__ pos,  // (B,N,2)
    const int*   __restrict__ mask, // (B,N) 0/1
    const float* __restrict__ W1,   // (2,64)
    const float* __restrict__ b1,   // (64)
    const float* __restrict__ W2,   // (64,64)
    const float* __restrict__ b2,   // (64)
    const float* __restrict__ W3,   // (64,16)
    const float* __restrict__ b3,   // (16)
    float* __restrict__ out)        // (B,16,N,N)
{
    __shared__ __align__(16) float uj[TJ][UST];    // u_j = pos_j @ W1
    __shared__ __align__(16) float uin[TI][UST];   // b1 - u_i
    __shared__ __align__(16) float outb[2][H_][UST]; // ping-pong output re-partition buffer

    const int b  = blockIdx.z;
    const int i0 = blockIdx.y * TI;
    const int j0 = blockIdx.x * TJ;
    const int tid = threadIdx.x;
    const int w = tid >> 6;      // wave 0..3
    const int l = tid & 63;
    const int g = l >> 4;        // quarter-wave group 0..3
    const int c = l & 15;        // lane-within-group 0..15

    // ---- Stage u = pos @ W1 for the 80 tokens this tile touches ----
    for (int it = tid; it < (TJ + TI) * 16; it += 256) {
        int r  = it >> 4;
        int kq = (it & 15) * 4;
        int tok = (r < TJ) ? (j0 + r) : (i0 + (r - TJ));
        float2 p  = *(const float2*)&pos[(b * N_ + tok) * 2];
        float4 w0 = *(const float4*)&W1[kq];
        float4 w1 = *(const float4*)&W1[HID_ + kq];
        float4 v;
        v.x = p.x * w0.x + p.y * w1.x;
        v.y = p.x * w0.y + p.y * w1.y;
        v.z = p.x * w0.z + p.y * w1.z;
        v.w = p.x * w0.w + p.y * w1.w;
        if (r < TJ) {
            *(float4*)&uj[r][kq] = v;
        } else {
            float4 bb = *(const float4*)&b1[kq];
            float4 t2 = { bb.x - v.x, bb.y - v.y, bb.z - v.z, bb.w - v.w };
            *(float4*)&uin[r - TJ][kq] = t2;
        }
    }

    // ---- Weight fragments (identity k-map for L2, permuted k-map for L3) ----
    bf16x8 W2f[2][4];   // A-frag of mfma(W2^T, h1^T): W2[32s+8g+e][16n+c]
    #pragma unroll
    for (int s = 0; s < 2; ++s)
        #pragma unroll
        for (int n = 0; n < 4; ++n)
            #pragma unroll
            for (int e = 0; e < 8; ++e)
                W2f[s][n][e] = f2bf(W2[(32*s + 8*g + e) * HID_ + 16*n + c]);

    bf16x8 W3g[2];      // B-frag, permuted k: hid = 32s + 16*(e>>2) + 4g + (e&3)
    #pragma unroll
    for (int s = 0; s < 2; ++s)
        #pragma unroll
        for (int e = 0; e < 8; ++e)
            W3g[s][e] = f2bf(W3[(32*s + 16*(e>>2) + 4*g + (e&3)) * H_ + c]);

    f32x4 b2v[4];
    #pragma unroll
    for (int n = 0; n < 4; ++n)
        b2v[n] = *(const f32x4*)&b2[16*n + 4*g];

    const float b3v = b3[c];
    const int* maskb = &mask[b * N_ + i0];
    // j-mask for the STORE mapping: lane covers j = j0 + 4c + q
    const int4 mjs = *(const int4*)&mask[b * N_ + j0 + 4*c];
    // store base: head = 4w+g, col = j0 + 4c
    const size_t storeBase = ((size_t)(b*H_ + 4*w + g) << 20) + (size_t)(j0 + 4*c);

    __syncthreads();

    // Hoist this lane's j-row of u (loop-invariant)
    const float* pj = &uj[16*w + c][0];
    const f32x4 pj00 = *(const f32x4*)&pj[8*g];
    const f32x4 pj01 = *(const f32x4*)&pj[8*g + 4];
    const f32x4 pj10 = *(const f32x4*)&pj[32 + 8*g];
    const f32x4 pj11 = *(const f32x4*)&pj[32 + 8*g + 4];

    for (int t = 0; t < TI; ++t) {
        const bool mi = (maskb[t] != 0);   // block-uniform

        if (!mi) {
            const float* uip = &uin[t][0];
            f32x4 ui00 = *(const f32x4*)&uip[8*g];
            f32x4 ui01 = *(const f32x4*)&uip[8*g + 4];
            f32x4 ui10 = *(const f32x4*)&uip[32 + 8*g];
            f32x4 ui11 = *(const f32x4*)&uip[32 + 8*g + 4];

            bf16x8 A1[2];
            #pragma unroll
            for (int e = 0; e < 4; ++e) {
                A1[0][e]     = f2bf(fmaxf(pj00[e] + ui00[e], 0.f));
                A1[0][e + 4] = f2bf(fmaxf(pj01[e] + ui01[e], 0.f));
                A1[1][e]     = f2bf(fmaxf(pj10[e] + ui10[e], 0.f));
                A1[1][e + 4] = f2bf(fmaxf(pj11[e] + ui11[e], 0.f));
            }

            // Layer2 transposed: lane (g,c) gets h2pre[pair c][hid 16n+4g+q]
            f32x4 acc[4];
            #pragma unroll
            for (int n = 0; n < 4; ++n) {
                acc[n] = __builtin_amdgcn_mfma_f32_16x16x32_bf16(W2f[0][n], A1[0], b2v[n], 0, 0, 0);
                acc[n] = __builtin_amdgcn_mfma_f32_16x16x32_bf16(W2f[1][n], A1[1], acc[n], 0, 0, 0);
            }

            // Layer3 A-frag register-only via permuted k-map
            bf16x8 A3[2];
            #pragma unroll
            for (int s = 0; s < 2; ++s)
                #pragma unroll
                for (int e = 0; e < 4; ++e) {
                    A3[s][e]     = f2bf(fmaxf(acc[2*s][e],     0.f));
                    A3[s][e + 4] = f2bf(fmaxf(acc[2*s + 1][e], 0.f));
                }

            f32x4 acc3 = { b3v, b3v, b3v, b3v };
            acc3 = __builtin_amdgcn_mfma_f32_16x16x32_bf16(A3[0], W3g[0], acc3, 0, 0, 0);
            acc3 = __builtin_amdgcn_mfma_f32_16x16x32_bf16(A3[1], W3g[1], acc3, 0, 0, 0);

            // deposit: lane holds out[pair 4g+q][head c] for j-col 16w+4g+q
            *(f32x4*)&outb[t & 1][c][16*w + 4*g] = acc3;
        }

        __syncthreads();   // uniform (mi is block-uniform)

        // store: lane covers head 4w+g, j = j0+4c+q -> 256B contiguous per head-row
        float4 o;
        if (mi) {
            o.x = 0.f; o.y = 0.f; o.z = 0.f; o.w = 0.f;
        } else {
            float4 v = *(const float4*)&outb[t & 1][4*w + g][4*c];
            o.x = mjs.x ? 0.f : v.x;
            o.y = mjs.y ? 0.f : v.y;
            o.z = mjs.z ? 0.f : v.z;
            o.w = mjs.w ? 0.f : v.w;
        }
        *(float4*)&out[storeBase + ((size_t)(i0 + t) << 10)] = o;
    }
}

extern "C" void kernel_launch(void* const* d_in, const int* in_sizes, int n_in,
                              void* d_out, int out_size, void* d_ws, size_t ws_size,
                              hipStream_t stream) {
    const float* pos  = (const float*)d_in[0];
    const int*   mask = (const int*)d_in[1];
    const float* W1   = (const float*)d_in[2];
    const float* b1   = (const float*)d_in[3];
    const float* W2   = (const float*)d_in[4];
    const float* b2   = (const float*)d_in[5];
    const float* W3   = (const float*)d_in[6];
    const float* b3   = (const float*)d_in[7];
    float* out = (float*)d_out;

    dim3 grid(N_ / TJ, N_ / TI, B_);
    RelativePositionalBias_kernel<<<grid, dim3(256), 0, stream>>>(
        pos, mask, W1, b1, W2, b2, W3, b3, out);
}

// Round 5
// 70.242 us; speedup vs baseline: 1.6140x; 1.1692x over previous
//
#include <hip/hip_runtime.h>
#include <hip/hip_bf16.h>
#include <hip/hip_fp16.h>

#define B_   4
#define N_   1024
#define H_   16
#define HID_ 64
#define TI   16
#define TJ   64
#define USJ  36   // uint stride for uj/uin rows (mult of 4 for b128 alignment, breaks bank alias)
#define USO  68   // float stride for outb rows

typedef float    f32x4  __attribute__((ext_vector_type(4)));
typedef __fp16   fp16x2 __attribute__((ext_vector_type(2)));   // type of cvt_pkrtz result
typedef _Float16 f16x8  __attribute__((ext_vector_type(8)));   // MFMA operand type
typedef unsigned int u32;

union F16x8U { u32 u[4]; f16x8 v; };

static __device__ __forceinline__ u32 pk(float a, float b) {
    union { fp16x2 f; u32 u; } r;
    r.f = __builtin_amdgcn_cvt_pkrtz(a, b);
    return r.u;
}
static __device__ __forceinline__ u32 pkadd_relu(u32 a, u32 b) {
    union { u32 u; fp16x2 f; } x, y, r;
    x.u = a; y.u = b;
    fp16x2 z = { (__fp16)0.f, (__fp16)0.f };
    fp16x2 s = x.f + y.f;
    r.f = __builtin_elementwise_max(s, z);
    return r.u;
}
static __device__ __forceinline__ u32 pkcvt_relu(float a, float b) {
    union { fp16x2 f; u32 u; } r;
    fp16x2 z = { (__fp16)0.f, (__fp16)0.f };
    fp16x2 s = __builtin_amdgcn_cvt_pkrtz(a, b);
    r.f = __builtin_elementwise_max(s, z);
    return r.u;
}

__global__ __launch_bounds__(256) void RelativePositionalBias_kernel(
    const float* __restrict__ pos,  // (B,N,2)
    const int*   __restrict__ mask, // (B,N) 0/1
    const float* __restrict__ W1,   // (2,64)
    const float* __restrict__ b1,   // (64)
    const float* __restrict__ W2,   // (64,64)
    const float* __restrict__ b2,   // (64)
    const float* __restrict__ W3,   // (64,16)
    const float* __restrict__ b3,   // (16)
    float* __restrict__ out)        // (B,16,N,N)
{
    __shared__ __align__(16) u32   ujL[TJ][USJ];        // u_j packed f16 pairs (k/2 uints)
    __shared__ __align__(16) u32   uinL[TI][USJ];       // (b1 - u_i) packed f16
    __shared__ __align__(16) float outb[2][2][H_][USO]; // ping-pong x 2 rows

    const int b  = blockIdx.z;
    const int i0 = blockIdx.y * TI;
    const int j0 = blockIdx.x * TJ;
    const int tid = threadIdx.x;
    const int w = tid >> 6;
    const int l = tid & 63;
    const int g = l >> 4;
    const int c = l & 15;

    // ---- Stage packed-f16 u for the 80 tokens (8 f16 per item) ----
    for (int it = tid; it < (TJ + TI) * 8; it += 256) {
        int r  = it >> 3;
        int qq = (it & 7) * 4;     // uint index base; covers k = 2*qq .. 2*qq+7
        int k0 = qq * 2;
        int tok = (r < TJ) ? (j0 + r) : (i0 + (r - TJ));
        float2 p  = *(const float2*)&pos[(b * N_ + tok) * 2];
        float4 a0 = *(const float4*)&W1[k0];
        float4 a1 = *(const float4*)&W1[k0 + 4];
        float4 c0 = *(const float4*)&W1[HID_ + k0];
        float4 c1 = *(const float4*)&W1[HID_ + k0 + 4];
        float u0 = p.x*a0.x + p.y*c0.x, u1 = p.x*a0.y + p.y*c0.y;
        float u2 = p.x*a0.z + p.y*c0.z, u3 = p.x*a0.w + p.y*c0.w;
        float u4 = p.x*a1.x + p.y*c1.x, u5 = p.x*a1.y + p.y*c1.y;
        float u6 = p.x*a1.z + p.y*c1.z, u7 = p.x*a1.w + p.y*c1.w;
        uint4 o;
        if (r < TJ) {
            o.x = pk(u0, u1); o.y = pk(u2, u3); o.z = pk(u4, u5); o.w = pk(u6, u7);
            *(uint4*)&ujL[r][qq] = o;
        } else {
            float4 ba = *(const float4*)&b1[k0];
            float4 bb = *(const float4*)&b1[k0 + 4];
            o.x = pk(ba.x - u0, ba.y - u1); o.y = pk(ba.z - u2, ba.w - u3);
            o.z = pk(bb.x - u4, bb.y - u5); o.w = pk(bb.z - u6, bb.w - u7);
            *(uint4*)&uinL[r - TJ][qq] = o;
        }
    }

    // ---- Weight fragments (f16). Identity k-map for L2, permuted for L3 ----
    F16x8U W2f[2][4];   // A-frag of mfma(W2^T, h1^T): W2[32s+8g+e][16n+c]
    #pragma unroll
    for (int s = 0; s < 2; ++s)
        #pragma unroll
        for (int n = 0; n < 4; ++n)
            #pragma unroll
            for (int e = 0; e < 8; ++e)
                W2f[s][n].v[e] = (_Float16)W2[(32*s + 8*g + e) * HID_ + 16*n + c];

    F16x8U W3g[2];      // B-frag, permuted k: hid = 32s + 16*(e>>2) + 4g + (e&3)
    #pragma unroll
    for (int s = 0; s < 2; ++s)
        #pragma unroll
        for (int e = 0; e < 8; ++e)
            W3g[s].v[e] = (_Float16)W3[(32*s + 16*(e>>2) + 4*g + (e&3)) * H_ + c];

    f32x4 b2v[4];
    #pragma unroll
    for (int n = 0; n < 4; ++n)
        b2v[n] = *(const f32x4*)&b2[16*n + 4*g];

    const float b3v = b3[c];
    const int* maskb = &mask[b * N_ + i0];
    const int4 mjs = *(const int4*)&mask[b * N_ + j0 + 4*c];           // store-side j-mask
    const size_t storeBase = ((size_t)(b*H_ + 4*w + g) << 20) + (size_t)(j0 + 4*c);

    __syncthreads();

    // Hoist this lane's packed j-row (uints 4g..4g+3 and 16+4g..): k = 8g+e (+32)
    const uint4 pj0 = *(const uint4*)&ujL[16*w + c][4*g];
    const uint4 pj1 = *(const uint4*)&ujL[16*w + c][16 + 4*g];

    for (int t = 0; t < TI; t += 2) {
        const int p = (t >> 1) & 1;
        const int mi0 = maskb[t], mi1 = maskb[t + 1];

        #pragma unroll
        for (int rr = 0; rr < 2; ++rr) {
            if ((rr ? mi1 : mi0)) continue;     // block-uniform skip
            const int tt = t + rr;

            uint4 uiA = *(const uint4*)&uinL[tt][4*g];
            uint4 uiB = *(const uint4*)&uinL[tt][16 + 4*g];

            // Layer1: h1 = relu(u_j + (b1-u_i)) in packed f16 — fragment-ready
            F16x8U A1[2];
            A1[0].u[0] = pkadd_relu(pj0.x, uiA.x);
            A1[0].u[1] = pkadd_relu(pj0.y, uiA.y);
            A1[0].u[2] = pkadd_relu(pj0.z, uiA.z);
            A1[0].u[3] = pkadd_relu(pj0.w, uiA.w);
            A1[1].u[0] = pkadd_relu(pj1.x, uiB.x);
            A1[1].u[1] = pkadd_relu(pj1.y, uiB.y);
            A1[1].u[2] = pkadd_relu(pj1.z, uiB.z);
            A1[1].u[3] = pkadd_relu(pj1.w, uiB.w);

            // Layer2 transposed: lane (g,c) gets h2pre[pair c][hid 16n+4g+q]
            f32x4 acc[4];
            #pragma unroll
            for (int n = 0; n < 4; ++n) {
                acc[n] = __builtin_amdgcn_mfma_f32_16x16x32_f16(W2f[0][n].v, A1[0].v, b2v[n], 0, 0, 0);
                acc[n] = __builtin_amdgcn_mfma_f32_16x16x32_f16(W2f[1][n].v, A1[1].v, acc[n], 0, 0, 0);
            }

            // Layer3 A-frag register-only via permuted k-map (cvt_pkrtz + packed relu)
            F16x8U A3[2];
            #pragma unroll
            for (int s = 0; s < 2; ++s) {
                A3[s].u[0] = pkcvt_relu(acc[2*s][0],     acc[2*s][1]);
                A3[s].u[1] = pkcvt_relu(acc[2*s][2],     acc[2*s][3]);
                A3[s].u[2] = pkcvt_relu(acc[2*s + 1][0], acc[2*s + 1][1]);
                A3[s].u[3] = pkcvt_relu(acc[2*s + 1][2], acc[2*s + 1][3]);
            }

            f32x4 acc3 = { b3v, b3v, b3v, b3v };
            acc3 = __builtin_amdgcn_mfma_f32_16x16x32_f16(A3[0].v, W3g[0].v, acc3, 0, 0, 0);
            acc3 = __builtin_amdgcn_mfma_f32_16x16x32_f16(A3[1].v, W3g[1].v, acc3, 0, 0, 0);

            // deposit: lane holds out[pair 4g+q][head c] for j-col 16w+4g+q
            *(f32x4*)&outb[p][rr][c][16*w + 4*g] = acc3;
        }

        __syncthreads();   // uniform barrier

        #pragma unroll
        for (int rr = 0; rr < 2; ++rr) {
            const int tt = t + rr;
            float4 o;
            if ((rr ? mi1 : mi0)) {
                o.x = 0.f; o.y = 0.f; o.z = 0.f; o.w = 0.f;
            } else {
                float4 v = *(const float4*)&outb[p][rr][4*w + g][4*c];
                o.x = mjs.x ? 0.f : v.x;
                o.y = mjs.y ? 0.f : v.y;
                o.z = mjs.z ? 0.f : v.z;
                o.w = mjs.w ? 0.f : v.w;
            }
            *(float4*)&out[storeBase + ((size_t)(i0 + tt) << 10)] = o;
        }
    }
}

extern "C" void kernel_launch(void* const* d_in, const int* in_sizes, int n_in,
                              void* d_out, int out_size, void* d_ws, size_t ws_size,
                              hipStream_t stream) {
    const float* pos  = (const float*)d_in[0];
    const int*   mask = (const int*)d_in[1];
    const float* W1   = (const float*)d_in[2];
    const float* b1   = (const float*)d_in[3];
    const float* W2   = (const float*)d_in[4];
    const float* b2   = (const float*)d_in[5];
    const float* W3   = (const float*)d_in[6];
    const float* b3   = (const float*)d_in[7];
    float* out = (float*)d_out;

    dim3 grid(N_ / TJ, N_ / TI, B_);
    RelativePositionalBias_kernel<<<grid, dim3(256), 0, stream>>>(
        pos, mask, W1, b1, W2, b2, W3, b3, out);
}

// Round 6
// 68.296 us; speedup vs baseline: 1.6600x; 1.0285x over previous
//
#include <hip/hip_runtime.h>
#include <hip/hip_bf16.h>
#include <hip/hip_fp16.h>

#define B_   4
#define N_   1024
#define H_   16
#define HID_ 64
#define TI   16
#define TJ   64
#define USJ  36   // uint stride for uj/uin rows
#define USO  68   // float stride for outb rows

typedef float    f32x4  __attribute__((ext_vector_type(4)));
typedef __fp16   fp16x2 __attribute__((ext_vector_type(2)));   // type of cvt_pkrtz result
typedef _Float16 f16x8  __attribute__((ext_vector_type(8)));   // MFMA operand type
typedef unsigned int u32;

union F16x8U { u32 u[4]; f16x8 v; };

static __device__ __forceinline__ u32 pk(float a, float b) {
    union { fp16x2 f; u32 u; } r;
    r.f = __builtin_amdgcn_cvt_pkrtz(a, b);
    return r.u;
}
static __device__ __forceinline__ u32 pkadd_relu(u32 a, u32 b) {
    union { u32 u; fp16x2 f; } x, y, r;
    x.u = a; y.u = b;
    fp16x2 z = { (__fp16)0.f, (__fp16)0.f };
    fp16x2 s = x.f + y.f;
    r.f = __builtin_elementwise_max(s, z);
    return r.u;
}
static __device__ __forceinline__ u32 pkcvt_relu(float a, float b) {
    union { fp16x2 f; u32 u; } r;
    fp16x2 z = { (__fp16)0.f, (__fp16)0.f };
    fp16x2 s = __builtin_amdgcn_cvt_pkrtz(a, b);
    r.f = __builtin_elementwise_max(s, z);
    return r.u;
}

__global__ __launch_bounds__(256) void RelativePositionalBias_kernel(
    const float* __restrict__ pos,  // (B,N,2)
    const int*   __restrict__ mask, // (B,N) 0/1
    const float* __restrict__ W1,   // (2,64)
    const float* __restrict__ b1,   // (64)
    const float* __restrict__ W2,   // (64,64)
    const float* __restrict__ b2,   // (64)
    const float* __restrict__ W3,   // (64,16)
    const float* __restrict__ b3,   // (16)
    float* __restrict__ out)        // (B,16,N,N)
{
    __shared__ __align__(16) u32   ujL[TJ][USJ];        // u_j packed f16
    __shared__ __align__(16) u32   uinL[TI][USJ];       // (b1 - u_i) packed f16
    __shared__ __align__(16) float outb[2][4][H_][USO]; // ping-pong x 4 rows

    const int b  = blockIdx.z;
    const int i0 = blockIdx.y * TI;
    const int j0 = blockIdx.x * TJ;
    const int tid = threadIdx.x;
    const int w = tid >> 6;
    const int l = tid & 63;
    const int g = l >> 4;
    const int c = l & 15;

    // ---- Stage packed-f16 u for the 80 tokens (8 f16 per item) ----
    for (int it = tid; it < (TJ + TI) * 8; it += 256) {
        int r  = it >> 3;
        int qq = (it & 7) * 4;     // uint index base; covers k = 2*qq .. 2*qq+7
        int k0 = qq * 2;
        int tok = (r < TJ) ? (j0 + r) : (i0 + (r - TJ));
        float2 p  = *(const float2*)&pos[(b * N_ + tok) * 2];
        float4 a0 = *(const float4*)&W1[k0];
        float4 a1 = *(const float4*)&W1[k0 + 4];
        float4 c0 = *(const float4*)&W1[HID_ + k0];
        float4 c1 = *(const float4*)&W1[HID_ + k0 + 4];
        float u0 = p.x*a0.x + p.y*c0.x, u1 = p.x*a0.y + p.y*c0.y;
        float u2 = p.x*a0.z + p.y*c0.z, u3 = p.x*a0.w + p.y*c0.w;
        float u4 = p.x*a1.x + p.y*c1.x, u5 = p.x*a1.y + p.y*c1.y;
        float u6 = p.x*a1.z + p.y*c1.z, u7 = p.x*a1.w + p.y*c1.w;
        uint4 o;
        if (r < TJ) {
            o.x = pk(u0, u1); o.y = pk(u2, u3); o.z = pk(u4, u5); o.w = pk(u6, u7);
            *(uint4*)&ujL[r][qq] = o;
        } else {
            float4 ba = *(const float4*)&b1[k0];
            float4 bb = *(const float4*)&b1[k0 + 4];
            o.x = pk(ba.x - u0, ba.y - u1); o.y = pk(ba.z - u2, ba.w - u3);
            o.z = pk(bb.x - u4, bb.y - u5); o.w = pk(bb.z - u6, bb.w - u7);
            *(uint4*)&uinL[r - TJ][qq] = o;
        }
    }

    // ---- Weight fragments (f16). Identity k-map for L2, permuted for L3 ----
    F16x8U W2f[2][4];   // A-frag of mfma(W2^T, h1^T): W2[32s+8g+e][16n+c]
    #pragma unroll
    for (int s = 0; s < 2; ++s)
        #pragma unroll
        for (int n = 0; n < 4; ++n)
            #pragma unroll
            for (int e = 0; e < 8; ++e)
                W2f[s][n].v[e] = (_Float16)W2[(32*s + 8*g + e) * HID_ + 16*n + c];

    F16x8U W3g[2];      // B-frag, permuted k: hid = 32s + 16*(e>>2) + 4g + (e&3)
    #pragma unroll
    for (int s = 0; s < 2; ++s)
        #pragma unroll
        for (int e = 0; e < 8; ++e)
            W3g[s].v[e] = (_Float16)W3[(32*s + 16*(e>>2) + 4*g + (e&3)) * H_ + c];

    f32x4 b2v[4];
    #pragma unroll
    for (int n = 0; n < 4; ++n)
        b2v[n] = *(const f32x4*)&b2[16*n + 4*g];

    const float b3v = b3[c];
    const int* maskb = &mask[b * N_ + i0];
    const int4 mjs = *(const int4*)&mask[b * N_ + j0 + 4*c];           // store-side j-mask
    const size_t storeBase = ((size_t)(b*H_ + 4*w + g) << 20) + (size_t)(j0 + 4*c);

    __syncthreads();

    // Hoist this lane's packed j-row: k = 8g+e (+32)
    const uint4 pj0 = *(const uint4*)&ujL[16*w + c][4*g];
    const uint4 pj1 = *(const uint4*)&ujL[16*w + c][16 + 4*g];

    for (int t = 0; t < TI; t += 4) {
        const int p = (t >> 2) & 1;
        const int4 mi4 = *(const int4*)&maskb[t];   // 16B-aligned (t mult of 4, i0 mult of 16)
        const int mi[4] = { mi4.x, mi4.y, mi4.z, mi4.w };

        // ---- compute + deposit 4 rows (independent chains -> ILP) ----
        #pragma unroll
        for (int rr = 0; rr < 4; ++rr) {
            if (mi[rr]) continue;                  // block-uniform skip
            const int tt = t + rr;

            uint4 uiA = *(const uint4*)&uinL[tt][4*g];
            uint4 uiB = *(const uint4*)&uinL[tt][16 + 4*g];

            // Layer1: h1 = relu(u_j + (b1-u_i)) packed f16 — fragment-ready
            F16x8U A1[2];
            A1[0].u[0] = pkadd_relu(pj0.x, uiA.x);
            A1[0].u[1] = pkadd_relu(pj0.y, uiA.y);
            A1[0].u[2] = pkadd_relu(pj0.z, uiA.z);
            A1[0].u[3] = pkadd_relu(pj0.w, uiA.w);
            A1[1].u[0] = pkadd_relu(pj1.x, uiB.x);
            A1[1].u[1] = pkadd_relu(pj1.y, uiB.y);
            A1[1].u[2] = pkadd_relu(pj1.z, uiB.z);
            A1[1].u[3] = pkadd_relu(pj1.w, uiB.w);

            // Layer2 transposed: lane (g,c) gets h2pre[pair c][hid 16n+4g+q]
            f32x4 acc[4];
            #pragma unroll
            for (int n = 0; n < 4; ++n) {
                acc[n] = __builtin_amdgcn_mfma_f32_16x16x32_f16(W2f[0][n].v, A1[0].v, b2v[n], 0, 0, 0);
                acc[n] = __builtin_amdgcn_mfma_f32_16x16x32_f16(W2f[1][n].v, A1[1].v, acc[n], 0, 0, 0);
            }

            // Layer3 A-frag register-only via permuted k-map
            F16x8U A3[2];
            #pragma unroll
            for (int s = 0; s < 2; ++s) {
                A3[s].u[0] = pkcvt_relu(acc[2*s][0],     acc[2*s][1]);
                A3[s].u[1] = pkcvt_relu(acc[2*s][2],     acc[2*s][3]);
                A3[s].u[2] = pkcvt_relu(acc[2*s + 1][0], acc[2*s + 1][1]);
                A3[s].u[3] = pkcvt_relu(acc[2*s + 1][2], acc[2*s + 1][3]);
            }

            f32x4 acc3 = { b3v, b3v, b3v, b3v };
            acc3 = __builtin_amdgcn_mfma_f32_16x16x32_f16(A3[0].v, W3g[0].v, acc3, 0, 0, 0);
            acc3 = __builtin_amdgcn_mfma_f32_16x16x32_f16(A3[1].v, W3g[1].v, acc3, 0, 0, 0);

            // deposit: lane holds out[pair 4g+q][head c] for j-col 16w+4g+q
            *(f32x4*)&outb[p][rr][c][16*w + 4*g] = acc3;
        }

        __syncthreads();   // one barrier per 4 rows; drains stores issued a phase ago

        // ---- store 4 rows: lane covers head 4w+g, j = j0+4c+q (256B runs) ----
        #pragma unroll
        for (int rr = 0; rr < 4; ++rr) {
            const int tt = t + rr;
            f32x4 o;
            if (mi[rr]) {
                o[0] = 0.f; o[1] = 0.f; o[2] = 0.f; o[3] = 0.f;
            } else {
                f32x4 v = *(const f32x4*)&outb[p][rr][4*w + g][4*c];
                o[0] = mjs.x ? 0.f : v[0];
                o[1] = mjs.y ? 0.f : v[1];
                o[2] = mjs.z ? 0.f : v[2];
                o[3] = mjs.w ? 0.f : v[3];
            }
            *(f32x4*)&out[storeBase + ((size_t)(i0 + tt) << 10)] = o;
        }
    }
}

extern "C" void kernel_launch(void* const* d_in, const int* in_sizes, int n_in,
                              void* d_out, int out_size, void* d_ws, size_t ws_size,
                              hipStream_t stream) {
    const float* pos  = (const float*)d_in[0];
    const int*   mask = (const int*)d_in[1];
    const float* W1   = (const float*)d_in[2];
    const float* b1   = (const float*)d_in[3];
    const float* W2   = (const float*)d_in[4];
    const float* b2   = (const float*)d_in[5];
    const float* W3   = (const float*)d_in[6];
    const float* b3   = (const float*)d_in[7];
    float* out = (float*)d_out;

    dim3 grid(N_ / TJ, N_ / TI, B_);
    RelativePositionalBias_kernel<<<grid, dim3(256), 0, stream>>>(
        pos, mask, W1, b1, W2, b2, W3, b3, out);
}